// Round 1
// 1015.959 us; speedup vs baseline: 1.0063x; 1.0063x over previous
//
#include <hip/hip_runtime.h>
#include <hip/hip_bf16.h>

typedef __hip_bfloat16 bf16;
typedef __attribute__((ext_vector_type(8))) short short8;
typedef __attribute__((ext_vector_type(4))) float floatx4;

#define BK 64
#define LDK 72  // old reg-staged path only

// async global->LDS, 16B per lane, linear dest (wave-uniform base + lane*16)
__device__ __forceinline__ void gload_lds16(const void* g, void* l) {
    __builtin_amdgcn_global_load_lds(
        (const __attribute__((address_space(1))) void*)g,
        (__attribute__((address_space(3))) void*)l, 16, 0, 0);
}

// ---------------------------------------------------------------------------
// NEW: bf16 NT GEMM via global_load_lds width=16 (m97 structure, 874TF-class).
// Requires M,N multiples of 128, K multiple of 64, bf16 A and B.
// LDS layout: linear [128][64] with XOR chunk swizzle baked into the global
// SOURCE address (rule #21: linear dest + inverse-swz source + swz read).
// chunk' = chunk ^ (row&7) -> fragment reads spread 2 lanes/bank (free).
// ---------------------------------------------------------------------------
template<bool OUT_BF16>
__global__ void __launch_bounds__(256) gemm_nt_lds(
    const bf16* __restrict__ A, const bf16* __restrict__ B, void* __restrict__ Cv,
    int M, int N, int K, int lda, int ldb, int ldc,
    long sA, long sB, long sC)
{
    __shared__ __align__(16) bf16 As[128 * 64];
    __shared__ __align__(16) bf16 Bs[128 * 64];

    int bx = blockIdx.x, by = blockIdx.y, bz = blockIdx.z;
    if (gridDim.x == 8 && gridDim.y == 8 && (gridDim.z & 7) == 0) {
        int hw  = bx + (by << 3) + (bz << 6);
        int xcd = hw & 7;
        int idx = hw >> 3;
        int zper = gridDim.z >> 3;
        bz = xcd * zper + (idx >> 6);
        int rem = idx & 63;
        by = rem >> 3;
        bx = rem & 7;
    }

    long aoff = (long)bz * sA;
    long boff = (long)bz * sB;
    long coff = (long)bz * sC;

    int m0 = by * 128;
    int n0 = bx * 128;
    int tid  = threadIdx.x;
    int lane = tid & 63;
    int wave = tid >> 6;
    int quad = lane >> 4;
    int l16  = lane & 15;
    int wm = (wave >> 1) * 64;
    int wn = (wave & 1) * 64;

    // staging: lane covers row (base + lane>>3), 16B chunk (lane&7), with the
    // source chunk XOR-swizzled by its row-within-8 so reads are conflict-free
    int lrow   = lane >> 3;            // 0..7
    int lchunk = (lane & 7) ^ lrow;    // swizzled source chunk
    int swz    = l16 & 7;              // = row&7 at fragment-read time

    const bf16* Abase = A + aoff + (long)m0 * lda;
    const bf16* Bbase = B + boff + (long)n0 * ldb;

    floatx4 acc[4][4] = {};
    const int nt = K / BK;

    for (int kt = 0; kt < nt; kt++) {
        __syncthreads();   // previous tile's LDS consumers done
        // stage tile kt: 4 calls A + 4 calls B per wave, 8 rows (1KB) per call
        long kofs = (long)kt * BK;
#pragma unroll
        for (int s = 0; s < 4; s++) {
            int r = wave * 32 + s * 8;
            gload_lds16(Abase + (long)(r + lrow) * lda + kofs + lchunk * 8, &As[r * 64]);
            gload_lds16(Bbase + (long)(r + lrow) * ldb + kofs + lchunk * 8, &Bs[r * 64]);
        }
        __syncthreads();   // compiler drains vmcnt(0) before the barrier

#pragma unroll
        for (int ks = 0; ks < 2; ks++) {
            short8 af[4], bfr[4];
#pragma unroll
            for (int i = 0; i < 4; i++) {
                int ri = wm + i * 16 + l16;
                af[i] = *(const short8*)(&As[ri * 64 + (((ks << 2) | quad) ^ swz) * 8]);
            }
#pragma unroll
            for (int j = 0; j < 4; j++) {
                int rj = wn + j * 16 + l16;
                bfr[j] = *(const short8*)(&Bs[rj * 64 + (((ks << 2) | quad) ^ swz) * 8]);
            }
#pragma unroll
            for (int i = 0; i < 4; i++)
#pragma unroll
                for (int j = 0; j < 4; j++)
                    acc[i][j] = __builtin_amdgcn_mfma_f32_16x16x32_bf16(af[i], bfr[j], acc[i][j], 0, 0, 0);
        }
    }

    // epilogue: C/D layout row = quad*4+reg, col = lane&15
#pragma unroll
    for (int i = 0; i < 4; i++) {
        int row = m0 + wm + i * 16 + quad * 4;
#pragma unroll
        for (int j = 0; j < 4; j++) {
            int col = n0 + wn + j * 16 + l16;
#pragma unroll
            for (int v = 0; v < 4; v++) {
                int r = row + v;
                float val = acc[i][j][v];
                if (OUT_BF16)
                    ((bf16*)Cv)[coff + (long)r * ldc + col] = __float2bfloat16(val);
                else
                    ((float*)Cv)[coff + (long)r * ldc + col] = val;
            }
        }
    }
}

// ---------------------------------------------------------------------------
// OLD reg-staged NT GEMM: kept only for the small Q/K projections
// (N=64 needs bounds guards; A is f32 converted at LDS-store time).
// ---------------------------------------------------------------------------
template<bool OUT_BF16, bool A_F32, bool B_F32>
__global__ void __launch_bounds__(256) gemm_nt(
    const void* __restrict__ Av, const void* __restrict__ Bv, void* __restrict__ Cv,
    int M, int N, int K, int lda, int ldb, int ldc,
    long sA, long sB, long sC)
{
    __shared__ __align__(16) bf16 As[128 * LDK];
    __shared__ __align__(16) bf16 Bs[128 * LDK];

    int bx = blockIdx.x, by = blockIdx.y, bz = blockIdx.z;
    if (gridDim.x == 8 && gridDim.y == 8 && (gridDim.z & 7) == 0) {
        int hw  = bx + (by << 3) + (bz << 6);
        int xcd = hw & 7;
        int idx = hw >> 3;
        int zper = gridDim.z >> 3;
        bz = xcd * zper + (idx >> 6);
        int rem = idx & 63;
        by = rem >> 3;
        bx = rem & 7;
    }

    long aoff = (long)bz * sA;
    long boff = (long)bz * sB;
    long coff = (long)bz * sC;

    int m0 = by * 128;
    int n0 = bx * 128;
    int tid  = threadIdx.x;
    int lane = tid & 63;
    int wave = tid >> 6;
    int quad = lane >> 4;
    int l16  = lane & 15;
    int wm = (wave >> 1) * 64;
    int wn = (wave & 1) * 64;

    int sr = tid >> 3;
    int sc = (tid & 7) * 8;

    floatx4 acc[4][4] = {};

    uint4  pa[4], pb[4];
    float4 pa0[4], pa1[4], pb0[4], pb1[4];

    const int nt = K / BK;

#pragma unroll
    for (int s = 0; s < 4; s++) {
        int r = sr + 32 * s;
        int gm = m0 + r;
        if (A_F32) {
            const float* p = (const float*)Av + aoff + (long)gm * lda + sc;
            if (gm < M) { pa0[s] = *(const float4*)p; pa1[s] = *(const float4*)(p + 4); }
            else { pa0[s] = {0,0,0,0}; pa1[s] = {0,0,0,0}; }
        } else {
            pa[s] = (gm < M) ? *(const uint4*)((const bf16*)Av + aoff + (long)gm * lda + sc)
                             : (uint4){0,0,0,0};
        }
        int gn = n0 + r;
        if (B_F32) {
            const float* p = (const float*)Bv + boff + (long)gn * ldb + sc;
            if (gn < N) { pb0[s] = *(const float4*)p; pb1[s] = *(const float4*)(p + 4); }
            else { pb0[s] = {0,0,0,0}; pb1[s] = {0,0,0,0}; }
        } else {
            pb[s] = (gn < N) ? *(const uint4*)((const bf16*)Bv + boff + (long)gn * ldb + sc)
                             : (uint4){0,0,0,0};
        }
    }

    for (int kt = 0; kt < nt; kt++) {
        __syncthreads();
#pragma unroll
        for (int s = 0; s < 4; s++) {
            int r = sr + 32 * s;
            if (A_F32) {
                bf16 t[8];
                t[0]=__float2bfloat16(pa0[s].x); t[1]=__float2bfloat16(pa0[s].y);
                t[2]=__float2bfloat16(pa0[s].z); t[3]=__float2bfloat16(pa0[s].w);
                t[4]=__float2bfloat16(pa1[s].x); t[5]=__float2bfloat16(pa1[s].y);
                t[6]=__float2bfloat16(pa1[s].z); t[7]=__float2bfloat16(pa1[s].w);
                *(uint4*)(&As[r * LDK + sc]) = *(const uint4*)t;
            } else {
                *(uint4*)(&As[r * LDK + sc]) = pa[s];
            }
            if (B_F32) {
                bf16 t[8];
                t[0]=__float2bfloat16(pb0[s].x); t[1]=__float2bfloat16(pb0[s].y);
                t[2]=__float2bfloat16(pb0[s].z); t[3]=__float2bfloat16(pb0[s].w);
                t[4]=__float2bfloat16(pb1[s].x); t[5]=__float2bfloat16(pb1[s].y);
                t[6]=__float2bfloat16(pb1[s].z); t[7]=__float2bfloat16(pb1[s].w);
                *(uint4*)(&Bs[r * LDK + sc]) = *(const uint4*)t;
            } else {
                *(uint4*)(&Bs[r * LDK + sc]) = pb[s];
            }
        }
        __syncthreads();

        if (kt + 1 < nt) {
            int k0 = (kt + 1) * BK;
#pragma unroll
            for (int s = 0; s < 4; s++) {
                int r = sr + 32 * s;
                int gm = m0 + r;
                if (A_F32) {
                    const float* p = (const float*)Av + aoff + (long)gm * lda + k0 + sc;
                    if (gm < M) { pa0[s] = *(const float4*)p; pa1[s] = *(const float4*)(p + 4); }
                    else { pa0[s] = {0,0,0,0}; pa1[s] = {0,0,0,0}; }
                } else {
                    pa[s] = (gm < M) ? *(const uint4*)((const bf16*)Av + aoff + (long)gm * lda + k0 + sc)
                                     : (uint4){0,0,0,0};
                }
                int gn = n0 + r;
                if (B_F32) {
                    const float* p = (const float*)Bv + boff + (long)gn * ldb + k0 + sc;
                    if (gn < N) { pb0[s] = *(const float4*)p; pb1[s] = *(const float4*)(p + 4); }
                    else { pb0[s] = {0,0,0,0}; pb1[s] = {0,0,0,0}; }
                } else {
                    pb[s] = (gn < N) ? *(const uint4*)((const bf16*)Bv + boff + (long)gn * ldb + k0 + sc)
                                     : (uint4){0,0,0,0};
                }
            }
        }

#pragma unroll
        for (int ks = 0; ks < 2; ks++) {
            short8 af[4], bfr[4];
#pragma unroll
            for (int i = 0; i < 4; i++)
                af[i] = *(const short8*)(&As[(wm + i * 16 + l16) * LDK + ks * 32 + quad * 8]);
#pragma unroll
            for (int j = 0; j < 4; j++)
                bfr[j] = *(const short8*)(&Bs[(wn + j * 16 + l16) * LDK + ks * 32 + quad * 8]);
#pragma unroll
            for (int i = 0; i < 4; i++)
#pragma unroll
                for (int j = 0; j < 4; j++)
                    acc[i][j] = __builtin_amdgcn_mfma_f32_16x16x32_bf16(af[i], bfr[j], acc[i][j], 0, 0, 0);
        }
    }

#pragma unroll
    for (int i = 0; i < 4; i++) {
        int row = m0 + wm + i * 16 + quad * 4;
#pragma unroll
        for (int j = 0; j < 4; j++) {
            int col = n0 + wn + j * 16 + l16;
            if (col >= N) continue;
#pragma unroll
            for (int v = 0; v < 4; v++) {
                int r = row + v;
                if (r < M) {
                    float val = acc[i][j][v];
                    if (OUT_BF16)
                        ((bf16*)Cv)[coff + (long)r * ldc + col] = __float2bfloat16(val);
                    else
                        ((float*)Cv)[coff + (long)r * ldc + col] = val;
                }
            }
        }
    }
}

// ---------------------------------------------------------------------------
// Fused QK^T + online softmax, ONE batch (round-4 PROVEN, unchanged).
// ---------------------------------------------------------------------------
__global__ void __launch_bounds__(256) attn_softmax(
    const bf16* __restrict__ Q, const bf16* __restrict__ Kb, bf16* __restrict__ Wts)
{
    __shared__ __align__(16) bf16 Ks[64 * 72];

    int h = blockIdx.y;
    const bf16* Qbh = Q  + (long)h * 262144;
    const bf16* Kbh = Kb + (long)h * 262144;
    bf16* W = Wts + (long)h * 1048576;

    int tid  = threadIdx.x;
    int lane = tid & 63;
    int wave = tid >> 6;
    int quad = lane >> 4;
    int l16  = lane & 15;
    int q0 = blockIdx.x * 64 + wave * 16;

    short8 a0 = *(const short8*)(Qbh + (long)(q0 + l16) * 64 + quad * 8);
    short8 a1 = *(const short8*)(Qbh + (long)(q0 + l16) * 64 + 32 + quad * 8);

    int sr = tid >> 3;
    int sc = (tid & 7) * 8;

    const float scale = 0.125f;
    float m_v[4] = {-1e30f, -1e30f, -1e30f, -1e30f};
    float l_v[4] = {0.f, 0.f, 0.f, 0.f};

    for (int t = 0; t < 16; t++) {
        __syncthreads();
        const bf16* src = Kbh + (long)(t * 64 + sr) * 64 + sc;
        *(uint4*)(&Ks[sr * 72 + sc])        = *(const uint4*)src;
        *(uint4*)(&Ks[(sr + 32) * 72 + sc]) = *(const uint4*)(src + 32 * 64);
        __syncthreads();
#pragma unroll
        for (int j = 0; j < 4; j++) {
            short8 b0 = *(const short8*)(&Ks[(j * 16 + l16) * 72 + quad * 8]);
            short8 b1 = *(const short8*)(&Ks[(j * 16 + l16) * 72 + 32 + quad * 8]);
            floatx4 acc = {0.f, 0.f, 0.f, 0.f};
            acc = __builtin_amdgcn_mfma_f32_16x16x32_bf16(a0, b0, acc, 0, 0, 0);
            acc = __builtin_amdgcn_mfma_f32_16x16x32_bf16(a1, b1, acc, 0, 0, 0);
#pragma unroll
            for (int v = 0; v < 4; v++) {
                float s  = acc[v] * scale;
                float nm = fmaxf(m_v[v], s);
                l_v[v] = l_v[v] * __expf(m_v[v] - nm) + __expf(s - nm);
                m_v[v] = nm;
            }
        }
    }

#pragma unroll
    for (int d = 1; d < 16; d <<= 1) {
#pragma unroll
        for (int v = 0; v < 4; v++) {
            float om = __shfl_xor(m_v[v], d);
            float ol = __shfl_xor(l_v[v], d);
            float nm = fmaxf(m_v[v], om);
            l_v[v] = l_v[v] * __expf(m_v[v] - nm) + ol * __expf(om - nm);
            m_v[v] = nm;
        }
    }
    float linv[4];
#pragma unroll
    for (int v = 0; v < 4; v++) linv[v] = 1.0f / l_v[v];

    for (int t = 0; t < 16; t++) {
        __syncthreads();
        const bf16* src = Kbh + (long)(t * 64 + sr) * 64 + sc;
        *(uint4*)(&Ks[sr * 72 + sc])        = *(const uint4*)src;
        *(uint4*)(&Ks[(sr + 32) * 72 + sc]) = *(const uint4*)(src + 32 * 64);
        __syncthreads();
#pragma unroll
        for (int j = 0; j < 4; j++) {
            short8 b0 = *(const short8*)(&Ks[(j * 16 + l16) * 72 + quad * 8]);
            short8 b1 = *(const short8*)(&Ks[(j * 16 + l16) * 72 + 32 + quad * 8]);
            floatx4 acc = {0.f, 0.f, 0.f, 0.f};
            acc = __builtin_amdgcn_mfma_f32_16x16x32_bf16(a0, b0, acc, 0, 0, 0);
            acc = __builtin_amdgcn_mfma_f32_16x16x32_bf16(a1, b1, acc, 0, 0, 0);
#pragma unroll
            for (int v = 0; v < 4; v++) {
                float w = __expf(acc[v] * scale - m_v[v]) * linv[v];
                W[(long)(q0 + quad * 4 + v) * 1024 + t * 64 + j * 16 + l16] = __float2bfloat16(w);
            }
        }
    }
}

// ---------------------------------------------------------------------------
__global__ void __launch_bounds__(256) cast_bf16_k(
    const float* __restrict__ in, bf16* __restrict__ out, int n4)
{
    int i = blockIdx.x * 256 + threadIdx.x;
    if (i >= n4) return;
    float4 v = ((const float4*)in)[i];
    bf16 t[4] = {__float2bfloat16(v.x), __float2bfloat16(v.y),
                 __float2bfloat16(v.z), __float2bfloat16(v.w)};
    ((uint2*)out)[i] = *(const uint2*)t;
}

__global__ void __launch_bounds__(256) transpose_cast(
    const float* __restrict__ in, bf16* __restrict__ out, int R, int C)
{
    __shared__ float t[32][33];
    int h = blockIdx.z;
    const float* inh = in + (long)h * R * C;
    bf16* outh = out + (long)h * R * C;
    int c0 = blockIdx.x * 32, r0 = blockIdx.y * 32;
    int tx = threadIdx.x, ty = threadIdx.y;
#pragma unroll
    for (int i = 0; i < 32; i += 8)
        t[ty + i][tx] = inh[(long)(r0 + ty + i) * C + c0 + tx];
    __syncthreads();
#pragma unroll
    for (int i = 0; i < 32; i += 8)
        outh[(long)(c0 + ty + i) * R + r0 + tx] = __float2bfloat16(t[tx][ty + i]);
}

// sum 16 fp32 partials of 1M elems each -> out (float4 per thread)
__global__ void __launch_bounds__(256) reduce16_k(
    const float* __restrict__ part, float* __restrict__ out)
{
    int i = blockIdx.x * 256 + threadIdx.x;
    float4 s = ((const float4*)part)[i];
#pragma unroll
    for (int c = 1; c < 16; c++) {
        float4 p = ((const float4*)part)[c * 262144 + i];
        s.x += p.x; s.y += p.y; s.z += p.z; s.w += p.w;
    }
    ((float4*)out)[i] = s;
}

// ---------------------------------------------------------------------------
// Workspace (MB, max 180 — proven):
//   wqt 0..2 | wkt 2..4 | wvt 4..36 | wob 36..68 | qb 68..76 | kb 76..84 |
//   vt_b 84..116 | wts_b 116..148 | att_b 148..180
//   out_part overlays 84..148 (vt_b/wts_b dead when final GEMM runs).
//   value_bf overlays 148..150 (att_b region; dead until PV GEMM, which runs
//   after vt GEMM has consumed value_bf — stream-ordered, safe).
// ---------------------------------------------------------------------------
extern "C" void kernel_launch(void* const* d_in, const int* in_sizes, int n_in,
                              void* d_out, int out_size, void* d_ws, size_t ws_size,
                              hipStream_t stream) {
    const float* query = (const float*)d_in[0];
    const float* key   = (const float*)d_in[1];
    const float* value = (const float*)d_in[2];
    const float* w_q   = (const float*)d_in[3];
    const float* w_k   = (const float*)d_in[4];
    const float* w_v   = (const float*)d_in[5];
    const float* w_o   = (const float*)d_in[6];
    float* out = (float*)d_out;

    char* ws = (char*)d_ws;
    const size_t MB = (size_t)1 << 20;
    bf16* wqt      = (bf16*)(ws + 0 * MB);
    bf16* wkt      = (bf16*)(ws + 2 * MB);
    bf16* wvt      = (bf16*)(ws + 4 * MB);
    bf16* wob      = (bf16*)(ws + 36 * MB);
    bf16* qb       = (bf16*)(ws + 68 * MB);
    bf16* kb       = (bf16*)(ws + 76 * MB);
    bf16* vt_b     = (bf16*)(ws + 84 * MB);
    bf16* wts_b    = (bf16*)(ws + 116 * MB);
    bf16* att_b    = (bf16*)(ws + 148 * MB);
    bf16* value_bf = (bf16*)(ws + 148 * MB);    // 2 MB overlay on att_b head
    float* out_part = (float*)(ws + 84 * MB);   // 64 MB overlay

    // weight prep
    transpose_cast<<<dim3(2, 32, 16),  dim3(32, 8), 0, stream>>>(w_q, wqt, 1024, 64);
    transpose_cast<<<dim3(2, 32, 16),  dim3(32, 8), 0, stream>>>(w_k, wkt, 1024, 64);
    transpose_cast<<<dim3(32, 32, 16), dim3(32, 8), 0, stream>>>(w_v, wvt, 1024, 1024);
    cast_bf16_k<<<16384, 256, 0, stream>>>(w_o, wob, 1024 * 16384 / 4);

    // Q/K projections (small, N=64 — old guarded reg-staged path)
    gemm_nt<true, true, false><<<dim3(1, 32, 16), 256, 0, stream>>>(
        query, wqt, qb, 4096, 64, 1024, 1024, 1024, 64, 0L, 65536L, 262144L);
    gemm_nt<true, true, false><<<dim3(1, 32, 16), 256, 0, stream>>>(
        key, wkt, kb, 4096, 64, 1024, 1024, 1024, 64, 0L, 65536L, 262144L);

    for (int b = 0; b < 4; b++) {
        // cast this batch's value to bf16 (enables global_load_lds path)
        cast_bf16_k<<<1024, 256, 0, stream>>>(value + (long)b * 1048576, value_bf, 262144);

        // V^T proj: vt_b[h][v][m] = wvt[h][v][d] . value_b[m][d]^T
        gemm_nt_lds<true><<<dim3(8, 8, 16), 256, 0, stream>>>(
            wvt, value_bf, vt_b,
            1024, 1024, 1024, 1024, 1024, 1024, 1048576L, 0L, 1048576L);

        // QK^T + softmax -> wts_b[h][q][m]
        attn_softmax<<<dim3(16, 16), 256, 0, stream>>>(
            qb + (long)b * 65536, kb + (long)b * 65536, wts_b);

        // PV^T: att_b[v][h*1024+q] = vt_b[h][v][m] . wts_b[h][q][m]^T
        gemm_nt_lds<true><<<dim3(8, 8, 16), 256, 0, stream>>>(
            vt_b, wts_b, att_b,
            1024, 1024, 1024, 1024, 1024, 16384, 1048576L, 1048576L, 1024L);

        // final split-K over heads: out_part[h][d][v] = wo[d][h*1024+q] . att_b[v][h*1024+q]^T
        gemm_nt_lds<false><<<dim3(8, 8, 16), 256, 0, stream>>>(
            wob, att_b, out_part,
            1024, 1024, 1024, 16384, 16384, 1024, 1024L, 1024L, 1048576L);

        // reduce 16 partials -> out[b]
        reduce16_k<<<1024, 256, 0, stream>>>(out_part, out + (long)b * 1048576);
    }

    (void)in_sizes; (void)n_in; (void)out_size; (void)ws_size;
}

// Round 2
// 911.194 us; speedup vs baseline: 1.1220x; 1.1150x over previous
//
#include <hip/hip_runtime.h>
#include <hip/hip_bf16.h>

typedef __hip_bfloat16 bf16;
typedef __attribute__((ext_vector_type(8))) short short8;
typedef __attribute__((ext_vector_type(4))) float floatx4;

#define BK 64
#define LDK 72  // old reg-staged path only

// async global->LDS, 16B per lane, linear dest (wave-uniform base + lane*16)
__device__ __forceinline__ void gload_lds16(const void* g, void* l) {
    __builtin_amdgcn_global_load_lds(
        (const __attribute__((address_space(1))) void*)g,
        (__attribute__((address_space(3))) void*)l, 16, 0, 0);
}

// ---------------------------------------------------------------------------
// 256x256-tile NT GEMM, 2-phase double-buffered pipeline (T3-minimum recipe):
//   prologue: STAGE(buf0,0); syncthreads
//   iter t:   STAGE(buf^1, t+1)  -- issue first, loads fly during compute
//             ds_read buf[cur]; MFMA (setprio-wrapped)
//             syncthreads (vmcnt(0)+lgkmcnt(0)+barrier) ; flip
// Requires M=N=1024 per z-slice, K mult of 64, bf16 A/B, grid (4,4,Z).
// 8 waves (2M x 4N), per-wave C = 128x64. LDS 128 KiB (2 dbuf x 32KB x A,B).
// Source-side XOR chunk swizzle (rule #21) keeps ds_read_b128 conflict-free.
// ---------------------------------------------------------------------------
template<bool OUT_BF16>
__global__ void __launch_bounds__(512) gemm_nt_256(
    const bf16* __restrict__ A, const bf16* __restrict__ B, void* __restrict__ Cv,
    int K, int lda, int ldb, int ldc,
    long sA, long sB, long sC)
{
    __shared__ __align__(16) bf16 As[2][256 * 64];
    __shared__ __align__(16) bf16 Bs[2][256 * 64];

    int bx = blockIdx.x, by = blockIdx.y, bz = blockIdx.z;
    // XCD swizzle: each XCD owns contiguous z-slices (bijective, Z%8==0)
    if (gridDim.x == 4 && gridDim.y == 4 && (gridDim.z & 7) == 0) {
        int hw  = bx + (by << 2) + (bz << 4);
        int xcd = hw & 7;
        int idx = hw >> 3;
        int per = (int)(gridDim.z >> 3) << 4;   // blocks per XCD
        int nh  = xcd * per + idx;
        bx = nh & 3; by = (nh >> 2) & 3; bz = nh >> 4;
    }

    long aoff = (long)bz * sA + (long)by * 256 * lda;
    long boff = (long)bz * sB + (long)bx * 256 * ldb;
    long coff = (long)bz * sC;

    int tid  = threadIdx.x;
    int lane = tid & 63;
    int wave = tid >> 6;           // 0..7
    int quad = lane >> 4;
    int l16  = lane & 15;
    int swz  = l16 & 7;            // row&7 at fragment-read time
    int wm = (wave >> 2) * 128;    // 2 M-waves
    int wn = (wave & 3) * 64;      // 4 N-waves

    // staging geometry: round s covers rows [s*64, s*64+64), this thread does
    // row s*64+srow, swizzled 16B chunk schunk; dest is linear (wave-uniform
    // base + lane*16B), source carries the inverse swizzle.
    int srow   = tid >> 3;                    // 0..63
    int schunk = (tid & 7) ^ (srow & 7);      // swizzled source chunk
    int dbase  = (wave << 3) * 64;            // wave*8 rows * 64 elems

    const bf16* Asrc = A + aoff;
    const bf16* Bsrc = B + boff;

    floatx4 acc[8][4] = {};
    const int nt = K / BK;

    auto STAGE = [&](int db, int kt) {
        long kofs = (long)kt * BK + schunk * 8;
#pragma unroll
        for (int s = 0; s < 4; s++) {
            int r = s * 64 + srow;
            gload_lds16(Asrc + (long)r * lda + kofs, &As[db][s * 64 * 64 + dbase]);
            gload_lds16(Bsrc + (long)r * ldb + kofs, &Bs[db][s * 64 * 64 + dbase]);
        }
    };

    // ---- prologue: stage tile 0, wait fully (vmcnt(0) via syncthreads) ----
    STAGE(0, 0);
    __syncthreads();

    int db = 0;
    for (int kt = 0; kt < nt; kt++) {
        // issue next-tile prefetch FIRST; loads stay in flight across MFMAs
        if (kt + 1 < nt) STAGE(db ^ 1, kt + 1);
        __builtin_amdgcn_sched_barrier(0);   // pin prefetch issue before compute

#pragma unroll
        for (int ks = 0; ks < 2; ks++) {
            int cch = ((ks << 2) | quad) ^ swz;
            short8 af[8], bfr[4];
#pragma unroll
            for (int i = 0; i < 8; i++)
                af[i] = *(const short8*)(&As[db][(wm + i * 16 + l16) * 64 + cch * 8]);
#pragma unroll
            for (int j = 0; j < 4; j++)
                bfr[j] = *(const short8*)(&Bs[db][(wn + j * 16 + l16) * 64 + cch * 8]);
            __builtin_amdgcn_s_setprio(1);
#pragma unroll
            for (int i = 0; i < 8; i++)
#pragma unroll
                for (int j = 0; j < 4; j++)
                    acc[i][j] = __builtin_amdgcn_mfma_f32_16x16x32_bf16(af[i], bfr[j], acc[i][j], 0, 0, 0);
            __builtin_amdgcn_s_setprio(0);
        }

        __syncthreads();   // drains this wave's prefetch (vmcnt 0) + all reads
        db ^= 1;
    }

    // epilogue: C/D layout row = quad*4+reg, col = lane&15
#pragma unroll
    for (int i = 0; i < 8; i++) {
        int row = by * 256 + wm + i * 16 + quad * 4;
#pragma unroll
        for (int j = 0; j < 4; j++) {
            int col = bx * 256 + wn + j * 16 + l16;
#pragma unroll
            for (int v = 0; v < 4; v++) {
                float val = acc[i][j][v];
                if (OUT_BF16)
                    ((bf16*)Cv)[coff + (long)(row + v) * ldc + col] = __float2bfloat16(val);
                else
                    ((float*)Cv)[coff + (long)(row + v) * ldc + col] = val;
            }
        }
    }
}

// ---------------------------------------------------------------------------
// OLD reg-staged NT GEMM: kept only for the small Q/K projections
// (N=64 needs bounds guards; A is f32 converted at LDS-store time).
// ---------------------------------------------------------------------------
template<bool OUT_BF16, bool A_F32, bool B_F32>
__global__ void __launch_bounds__(256) gemm_nt(
    const void* __restrict__ Av, const void* __restrict__ Bv, void* __restrict__ Cv,
    int M, int N, int K, int lda, int ldb, int ldc,
    long sA, long sB, long sC)
{
    __shared__ __align__(16) bf16 As[128 * LDK];
    __shared__ __align__(16) bf16 Bs[128 * LDK];

    int bx = blockIdx.x, by = blockIdx.y, bz = blockIdx.z;

    long aoff = (long)bz * sA;
    long boff = (long)bz * sB;
    long coff = (long)bz * sC;

    int m0 = by * 128;
    int n0 = bx * 128;
    int tid  = threadIdx.x;
    int lane = tid & 63;
    int wave = tid >> 6;
    int quad = lane >> 4;
    int l16  = lane & 15;
    int wm = (wave >> 1) * 64;
    int wn = (wave & 1) * 64;

    int sr = tid >> 3;
    int sc = (tid & 7) * 8;

    floatx4 acc[4][4] = {};

    uint4  pa[4], pb[4];
    float4 pa0[4], pa1[4], pb0[4], pb1[4];

    const int nt = K / BK;

#pragma unroll
    for (int s = 0; s < 4; s++) {
        int r = sr + 32 * s;
        int gm = m0 + r;
        if (A_F32) {
            const float* p = (const float*)Av + aoff + (long)gm * lda + sc;
            if (gm < M) { pa0[s] = *(const float4*)p; pa1[s] = *(const float4*)(p + 4); }
            else { pa0[s] = {0,0,0,0}; pa1[s] = {0,0,0,0}; }
        } else {
            pa[s] = (gm < M) ? *(const uint4*)((const bf16*)Av + aoff + (long)gm * lda + sc)
                             : (uint4){0,0,0,0};
        }
        int gn = n0 + r;
        if (B_F32) {
            const float* p = (const float*)Bv + boff + (long)gn * ldb + sc;
            if (gn < N) { pb0[s] = *(const float4*)p; pb1[s] = *(const float4*)(p + 4); }
            else { pb0[s] = {0,0,0,0}; pb1[s] = {0,0,0,0}; }
        } else {
            pb[s] = (gn < N) ? *(const uint4*)((const bf16*)Bv + boff + (long)gn * ldb + sc)
                             : (uint4){0,0,0,0};
        }
    }

    for (int kt = 0; kt < nt; kt++) {
        __syncthreads();
#pragma unroll
        for (int s = 0; s < 4; s++) {
            int r = sr + 32 * s;
            if (A_F32) {
                bf16 t[8];
                t[0]=__float2bfloat16(pa0[s].x); t[1]=__float2bfloat16(pa0[s].y);
                t[2]=__float2bfloat16(pa0[s].z); t[3]=__float2bfloat16(pa0[s].w);
                t[4]=__float2bfloat16(pa1[s].x); t[5]=__float2bfloat16(pa1[s].y);
                t[6]=__float2bfloat16(pa1[s].z); t[7]=__float2bfloat16(pa1[s].w);
                *(uint4*)(&As[r * LDK + sc]) = *(const uint4*)t;
            } else {
                *(uint4*)(&As[r * LDK + sc]) = pa[s];
            }
            if (B_F32) {
                bf16 t[8];
                t[0]=__float2bfloat16(pb0[s].x); t[1]=__float2bfloat16(pb0[s].y);
                t[2]=__float2bfloat16(pb0[s].z); t[3]=__float2bfloat16(pb0[s].w);
                t[4]=__float2bfloat16(pb1[s].x); t[5]=__float2bfloat16(pb1[s].y);
                t[6]=__float2bfloat16(pb1[s].z); t[7]=__float2bfloat16(pb1[s].w);
                *(uint4*)(&Bs[r * LDK + sc]) = *(const uint4*)t;
            } else {
                *(uint4*)(&Bs[r * LDK + sc]) = pb[s];
            }
        }
        __syncthreads();

        if (kt + 1 < nt) {
            int k0 = (kt + 1) * BK;
#pragma unroll
            for (int s = 0; s < 4; s++) {
                int r = sr + 32 * s;
                int gm = m0 + r;
                if (A_F32) {
                    const float* p = (const float*)Av + aoff + (long)gm * lda + k0 + sc;
                    if (gm < M) { pa0[s] = *(const float4*)p; pa1[s] = *(const float4*)(p + 4); }
                    else { pa0[s] = {0,0,0,0}; pa1[s] = {0,0,0,0}; }
                } else {
                    pa[s] = (gm < M) ? *(const uint4*)((const bf16*)Av + aoff + (long)gm * lda + k0 + sc)
                                     : (uint4){0,0,0,0};
                }
                int gn = n0 + r;
                if (B_F32) {
                    const float* p = (const float*)Bv + boff + (long)gn * ldb + k0 + sc;
                    if (gn < N) { pb0[s] = *(const float4*)p; pb1[s] = *(const float4*)(p + 4); }
                    else { pb0[s] = {0,0,0,0}; pb1[s] = {0,0,0,0}; }
                } else {
                    pb[s] = (gn < N) ? *(const uint4*)((const bf16*)Bv + boff + (long)gn * ldb + k0 + sc)
                                     : (uint4){0,0,0,0};
                }
            }
        }

#pragma unroll
        for (int ks = 0; ks < 2; ks++) {
            short8 af[4], bfr[4];
#pragma unroll
            for (int i = 0; i < 4; i++)
                af[i] = *(const short8*)(&As[(wm + i * 16 + l16) * LDK + ks * 32 + quad * 8]);
#pragma unroll
            for (int j = 0; j < 4; j++)
                bfr[j] = *(const short8*)(&Bs[(wn + j * 16 + l16) * LDK + ks * 32 + quad * 8]);
#pragma unroll
            for (int i = 0; i < 4; i++)
#pragma unroll
                for (int j = 0; j < 4; j++)
                    acc[i][j] = __builtin_amdgcn_mfma_f32_16x16x32_bf16(af[i], bfr[j], acc[i][j], 0, 0, 0);
        }
    }

#pragma unroll
    for (int i = 0; i < 4; i++) {
        int row = m0 + wm + i * 16 + quad * 4;
#pragma unroll
        for (int j = 0; j < 4; j++) {
            int col = n0 + wn + j * 16 + l16;
            if (col >= N) continue;
#pragma unroll
            for (int v = 0; v < 4; v++) {
                int r = row + v;
                if (r < M) {
                    float val = acc[i][j][v];
                    if (OUT_BF16)
                        ((bf16*)Cv)[coff + (long)r * ldc + col] = __float2bfloat16(val);
                    else
                        ((float*)Cv)[coff + (long)r * ldc + col] = val;
                }
            }
        }
    }
}

// ---------------------------------------------------------------------------
// Fused QK^T + online softmax, ONE batch (round-4 PROVEN, unchanged).
// ---------------------------------------------------------------------------
__global__ void __launch_bounds__(256) attn_softmax(
    const bf16* __restrict__ Q, const bf16* __restrict__ Kb, bf16* __restrict__ Wts)
{
    __shared__ __align__(16) bf16 Ks[64 * 72];

    int h = blockIdx.y;
    const bf16* Qbh = Q  + (long)h * 262144;
    const bf16* Kbh = Kb + (long)h * 262144;
    bf16* W = Wts + (long)h * 1048576;

    int tid  = threadIdx.x;
    int lane = tid & 63;
    int wave = tid >> 6;
    int quad = lane >> 4;
    int l16  = lane & 15;
    int q0 = blockIdx.x * 64 + wave * 16;

    short8 a0 = *(const short8*)(Qbh + (long)(q0 + l16) * 64 + quad * 8);
    short8 a1 = *(const short8*)(Qbh + (long)(q0 + l16) * 64 + 32 + quad * 8);

    int sr = tid >> 3;
    int sc = (tid & 7) * 8;

    const float scale = 0.125f;
    float m_v[4] = {-1e30f, -1e30f, -1e30f, -1e30f};
    float l_v[4] = {0.f, 0.f, 0.f, 0.f};

    for (int t = 0; t < 16; t++) {
        __syncthreads();
        const bf16* src = Kbh + (long)(t * 64 + sr) * 64 + sc;
        *(uint4*)(&Ks[sr * 72 + sc])        = *(const uint4*)src;
        *(uint4*)(&Ks[(sr + 32) * 72 + sc]) = *(const uint4*)(src + 32 * 64);
        __syncthreads();
#pragma unroll
        for (int j = 0; j < 4; j++) {
            short8 b0 = *(const short8*)(&Ks[(j * 16 + l16) * 72 + quad * 8]);
            short8 b1 = *(const short8*)(&Ks[(j * 16 + l16) * 72 + 32 + quad * 8]);
            floatx4 acc = {0.f, 0.f, 0.f, 0.f};
            acc = __builtin_amdgcn_mfma_f32_16x16x32_bf16(a0, b0, acc, 0, 0, 0);
            acc = __builtin_amdgcn_mfma_f32_16x16x32_bf16(a1, b1, acc, 0, 0, 0);
#pragma unroll
            for (int v = 0; v < 4; v++) {
                float s  = acc[v] * scale;
                float nm = fmaxf(m_v[v], s);
                l_v[v] = l_v[v] * __expf(m_v[v] - nm) + __expf(s - nm);
                m_v[v] = nm;
            }
        }
    }

#pragma unroll
    for (int d = 1; d < 16; d <<= 1) {
#pragma unroll
        for (int v = 0; v < 4; v++) {
            float om = __shfl_xor(m_v[v], d);
            float ol = __shfl_xor(l_v[v], d);
            float nm = fmaxf(m_v[v], om);
            l_v[v] = l_v[v] * __expf(m_v[v] - nm) + ol * __expf(om - nm);
            m_v[v] = nm;
        }
    }
    float linv[4];
#pragma unroll
    for (int v = 0; v < 4; v++) linv[v] = 1.0f / l_v[v];

    for (int t = 0; t < 16; t++) {
        __syncthreads();
        const bf16* src = Kbh + (long)(t * 64 + sr) * 64 + sc;
        *(uint4*)(&Ks[sr * 72 + sc])        = *(const uint4*)src;
        *(uint4*)(&Ks[(sr + 32) * 72 + sc]) = *(const uint4*)(src + 32 * 64);
        __syncthreads();
#pragma unroll
        for (int j = 0; j < 4; j++) {
            short8 b0 = *(const short8*)(&Ks[(j * 16 + l16) * 72 + quad * 8]);
            short8 b1 = *(const short8*)(&Ks[(j * 16 + l16) * 72 + 32 + quad * 8]);
            floatx4 acc = {0.f, 0.f, 0.f, 0.f};
            acc = __builtin_amdgcn_mfma_f32_16x16x32_bf16(a0, b0, acc, 0, 0, 0);
            acc = __builtin_amdgcn_mfma_f32_16x16x32_bf16(a1, b1, acc, 0, 0, 0);
#pragma unroll
            for (int v = 0; v < 4; v++) {
                float w = __expf(acc[v] * scale - m_v[v]) * linv[v];
                W[(long)(q0 + quad * 4 + v) * 1024 + t * 64 + j * 16 + l16] = __float2bfloat16(w);
            }
        }
    }
}

// ---------------------------------------------------------------------------
__global__ void __launch_bounds__(256) cast_bf16_k(
    const float* __restrict__ in, bf16* __restrict__ out, int n4)
{
    int i = blockIdx.x * 256 + threadIdx.x;
    if (i >= n4) return;
    float4 v = ((const float4*)in)[i];
    bf16 t[4] = {__float2bfloat16(v.x), __float2bfloat16(v.y),
                 __float2bfloat16(v.z), __float2bfloat16(v.w)};
    ((uint2*)out)[i] = *(const uint2*)t;
}

__global__ void __launch_bounds__(256) transpose_cast(
    const float* __restrict__ in, bf16* __restrict__ out, int R, int C)
{
    __shared__ float t[32][33];
    int h = blockIdx.z;
    const float* inh = in + (long)h * R * C;
    bf16* outh = out + (long)h * R * C;
    int c0 = blockIdx.x * 32, r0 = blockIdx.y * 32;
    int tx = threadIdx.x, ty = threadIdx.y;
#pragma unroll
    for (int i = 0; i < 32; i += 8)
        t[ty + i][tx] = inh[(long)(r0 + ty + i) * C + c0 + tx];
    __syncthreads();
#pragma unroll
    for (int i = 0; i < 32; i += 8)
        outh[(long)(c0 + ty + i) * R + r0 + tx] = __float2bfloat16(t[tx][ty + i]);
}

// sum 16 fp32 partials of 1M elems each -> out (float4 per thread)
__global__ void __launch_bounds__(256) reduce16_k(
    const float* __restrict__ part, float* __restrict__ out)
{
    int i = blockIdx.x * 256 + threadIdx.x;
    float4 s = ((const float4*)part)[i];
#pragma unroll
    for (int c = 1; c < 16; c++) {
        float4 p = ((const float4*)part)[c * 262144 + i];
        s.x += p.x; s.y += p.y; s.z += p.z; s.w += p.w;
    }
    ((float4*)out)[i] = s;
}

// ---------------------------------------------------------------------------
// Workspace (MB, max 180 — proven):
//   wqt 0..2 | wkt 2..4 | wvt 4..36 | wob 36..68 | qb 68..76 | kb 76..84 |
//   vt_b 84..116 | wts_b 116..148 | att_b 148..180
//   out_part overlays 84..148 (vt_b/wts_b dead when final GEMM runs).
//   value_bf overlays 148..150 (att_b region; dead until PV GEMM, which runs
//   after vt GEMM has consumed value_bf — stream-ordered, safe).
// ---------------------------------------------------------------------------
extern "C" void kernel_launch(void* const* d_in, const int* in_sizes, int n_in,
                              void* d_out, int out_size, void* d_ws, size_t ws_size,
                              hipStream_t stream) {
    const float* query = (const float*)d_in[0];
    const float* key   = (const float*)d_in[1];
    const float* value = (const float*)d_in[2];
    const float* w_q   = (const float*)d_in[3];
    const float* w_k   = (const float*)d_in[4];
    const float* w_v   = (const float*)d_in[5];
    const float* w_o   = (const float*)d_in[6];
    float* out = (float*)d_out;

    char* ws = (char*)d_ws;
    const size_t MB = (size_t)1 << 20;
    bf16* wqt      = (bf16*)(ws + 0 * MB);
    bf16* wkt      = (bf16*)(ws + 2 * MB);
    bf16* wvt      = (bf16*)(ws + 4 * MB);
    bf16* wob      = (bf16*)(ws + 36 * MB);
    bf16* qb       = (bf16*)(ws + 68 * MB);
    bf16* kb       = (bf16*)(ws + 76 * MB);
    bf16* vt_b     = (bf16*)(ws + 84 * MB);
    bf16* wts_b    = (bf16*)(ws + 116 * MB);
    bf16* att_b    = (bf16*)(ws + 148 * MB);
    bf16* value_bf = (bf16*)(ws + 148 * MB);    // 2 MB overlay on att_b head
    float* out_part = (float*)(ws + 84 * MB);   // 64 MB overlay

    // weight prep
    transpose_cast<<<dim3(2, 32, 16),  dim3(32, 8), 0, stream>>>(w_q, wqt, 1024, 64);
    transpose_cast<<<dim3(2, 32, 16),  dim3(32, 8), 0, stream>>>(w_k, wkt, 1024, 64);
    transpose_cast<<<dim3(32, 32, 16), dim3(32, 8), 0, stream>>>(w_v, wvt, 1024, 1024);
    cast_bf16_k<<<16384, 256, 0, stream>>>(w_o, wob, 1024 * 16384 / 4);

    // Q/K projections (small, N=64 — old guarded reg-staged path)
    gemm_nt<true, true, false><<<dim3(1, 32, 16), 256, 0, stream>>>(
        query, wqt, qb, 4096, 64, 1024, 1024, 1024, 64, 0L, 65536L, 262144L);
    gemm_nt<true, true, false><<<dim3(1, 32, 16), 256, 0, stream>>>(
        key, wkt, kb, 4096, 64, 1024, 1024, 1024, 64, 0L, 65536L, 262144L);

    for (int b = 0; b < 4; b++) {
        // cast this batch's value to bf16 (enables global_load_lds path)
        cast_bf16_k<<<1024, 256, 0, stream>>>(value + (long)b * 1048576, value_bf, 262144);

        // V^T proj: vt_b[h][v][m] = wvt[h][v][d] . value_b[m][d]^T
        gemm_nt_256<true><<<dim3(4, 4, 16), 512, 0, stream>>>(
            wvt, value_bf, vt_b,
            1024, 1024, 1024, 1024, 1048576L, 0L, 1048576L);

        // QK^T + softmax -> wts_b[h][q][m]
        attn_softmax<<<dim3(16, 16), 256, 0, stream>>>(
            qb + (long)b * 65536, kb + (long)b * 65536, wts_b);

        // PV^T: att_b[v][h*1024+q] = vt_b[h][v][m] . wts_b[h][q][m]^T
        gemm_nt_256<true><<<dim3(4, 4, 16), 512, 0, stream>>>(
            vt_b, wts_b, att_b,
            1024, 1024, 1024, 16384, 1048576L, 1048576L, 1024L);

        // final split-K over heads: out_part[h][d][v] = wo[d][h*1024+q] . att_b[v][h*1024+q]^T
        gemm_nt_256<false><<<dim3(4, 4, 16), 512, 0, stream>>>(
            wob, att_b, out_part,
            1024, 16384, 16384, 1024, 1024L, 1024L, 1048576L);

        // reduce 16 partials -> out[b]
        reduce16_k<<<1024, 256, 0, stream>>>(out_part, out + (long)b * 1048576);
    }

    (void)in_sizes; (void)n_in; (void)out_size; (void)ws_size;
}

// Round 3
// 859.815 us; speedup vs baseline: 1.1891x; 1.0598x over previous
//
#include <hip/hip_runtime.h>
#include <hip/hip_bf16.h>

typedef __hip_bfloat16 bf16;
typedef __attribute__((ext_vector_type(8))) short short8;
typedef __attribute__((ext_vector_type(4))) float floatx4;

#define BK 64
#define LDK 72  // old reg-staged path only

// async global->LDS, 16B per lane, linear dest (wave-uniform base + lane*16)
__device__ __forceinline__ void gload_lds16(const void* g, void* l) {
    __builtin_amdgcn_global_load_lds(
        (const __attribute__((address_space(1))) void*)g,
        (__attribute__((address_space(3))) void*)l, 16, 0, 0);
}

// ---------------------------------------------------------------------------
// 256x256-tile NT GEMM, 8-phase counted-vmcnt pipeline (T3+T4+T5).
//   Per K-tile: 4 phases, one C-quadrant (16 MFMA) each.
//   Half-tiles (Ah0=A rows0-127, Ah1, Bh0, Bh1) staged 1/phase, rotating
//   in-place over 2 LDS buffers:
//     p0: read af_lo(8)+bf01(4); stage (kt+1,Ah1)->buf^1; MFMA i0-3,j0-1
//     p1: read bf23(4);          stage (kt+1,Bh0)->buf^1; MFMA i0-3,j2-3
//     p2: read af_hi(8);         stage (kt+1,Bh1)->buf^1; MFMA i4-7,j2-3
//         BARRIER (af_hi readers of buf done -> p3 may overwrite Ah0)
//     p3:                        stage (kt+2,Ah0)->buf;   MFMA i4-7,j0-1
//         vmcnt(2) [vmcnt(0) entering last K-tile]; BARRIER; flip
//   Race ledger: every stage target region's last reader is >=1 barrier
//   before the stage issue; every read is covered by the boundary
//   vmcnt+barrier (vmcnt(2) leaves only the newest half-tile in flight).
// Requires M=N=1024 per z-slice, K mult of 64 and K>=128, bf16 A/B,
// grid (4,4,Z). 8 waves (2M x 4N), per-wave C = 128x64. LDS 128 KiB.
// Source-side XOR chunk swizzle (rule #21) keeps ds_read_b128 conflict-free.
// ---------------------------------------------------------------------------
template<bool OUT_BF16>
__global__ void __launch_bounds__(512) gemm_nt_256(
    const bf16* __restrict__ A, const bf16* __restrict__ B, void* __restrict__ Cv,
    int K, int lda, int ldb, int ldc,
    long sA, long sB, long sC)
{
    __shared__ __align__(16) bf16 As[2][256 * 64];
    __shared__ __align__(16) bf16 Bs[2][256 * 64];

    int bx = blockIdx.x, by = blockIdx.y, bz = blockIdx.z;
    // XCD swizzle: each XCD owns contiguous z-slices (bijective, Z%8==0)
    if (gridDim.x == 4 && gridDim.y == 4 && (gridDim.z & 7) == 0) {
        int hw  = bx + (by << 2) + (bz << 4);
        int xcd = hw & 7;
        int idx = hw >> 3;
        int per = (int)(gridDim.z >> 3) << 4;   // blocks per XCD
        int nh  = xcd * per + idx;
        bx = nh & 3; by = (nh >> 2) & 3; bz = nh >> 4;
    }

    long aoff = (long)bz * sA + (long)by * 256 * lda;
    long boff = (long)bz * sB + (long)bx * 256 * ldb;
    long coff = (long)bz * sC;

    int tid  = threadIdx.x;
    int lane = tid & 63;
    int wave = tid >> 6;           // 0..7
    int quad = lane >> 4;
    int l16  = lane & 15;
    int swz  = l16 & 7;            // row&7 at fragment-read time
    int wm = (wave >> 2) * 128;    // 2 M-waves
    int wn = (wave & 3) * 64;      // 4 N-waves

    // staging geometry: per half-tile (128 rows x 64 K), 2 rounds of
    // 512 threads x 16B. Dest linear (wave-uniform base + lane*16B);
    // source carries the inverse XOR swizzle.
    int srow   = tid >> 3;                    // 0..63
    int schunk = (tid & 7) ^ (srow & 7);      // swizzled source chunk
    int dwb    = (wave << 3) * 64;            // wave*8 rows * 64 elems

    const bf16* Asrc = A + aoff;
    const bf16* Bsrc = B + boff;

    floatx4 acc[8][4] = {};
    const int nt = K / BK;   // REQUIRES nt >= 2

    auto STAGE_A = [&](int db, int half, int kt) {
        long kofs = (long)kt * BK + schunk * 8;
#pragma unroll
        for (int s = 0; s < 2; s++) {
            int r = half * 128 + s * 64;
            gload_lds16(Asrc + (long)(r + srow) * lda + kofs, &As[db][r * 64 + dwb]);
        }
    };
    auto STAGE_B = [&](int db, int half, int kt) {
        long kofs = (long)kt * BK + schunk * 8;
#pragma unroll
        for (int s = 0; s < 2; s++) {
            int r = half * 128 + s * 64;
            gload_lds16(Bsrc + (long)(r + srow) * ldb + kofs, &Bs[db][r * 64 + dwb]);
        }
    };

    // ---- prologue: K-tile 0 fully + (1, Ah0); wait leaves newest in flight
    STAGE_A(0, 0, 0); STAGE_A(0, 1, 0); STAGE_B(0, 0, 0); STAGE_B(0, 1, 0);
    STAGE_A(1, 0, 1);
    asm volatile("s_waitcnt vmcnt(2)" ::: "memory");
    asm volatile("s_barrier" ::: "memory");

    short8 af[4][2], bf[4][2];
    int db = 0;
    for (int kt = 0; kt < nt; kt++) {
        const bf16* as = As[db];
        const bf16* bs = Bs[db];
        bool st1 = (kt + 1 < nt);
        bool st2 = (kt + 2 < nt);

        // ---- p0: read af_lo + bf01 ; stage (kt+1, Ah1) ; MFMA i0-3 j0-1
#pragma unroll
        for (int i = 0; i < 4; i++)
#pragma unroll
            for (int ks = 0; ks < 2; ks++)
                af[i][ks] = *(const short8*)(&as[(wm + i * 16 + l16) * 64 + ((((ks << 2) | quad)) ^ swz) * 8]);
#pragma unroll
        for (int j = 0; j < 2; j++)
#pragma unroll
            for (int ks = 0; ks < 2; ks++)
                bf[j][ks] = *(const short8*)(&bs[(wn + j * 16 + l16) * 64 + ((((ks << 2) | quad)) ^ swz) * 8]);
        if (st1) STAGE_A(db ^ 1, 1, kt + 1);
        __builtin_amdgcn_sched_barrier(0);
        __builtin_amdgcn_s_setprio(1);
#pragma unroll
        for (int i = 0; i < 4; i++)
#pragma unroll
            for (int j = 0; j < 2; j++)
#pragma unroll
                for (int ks = 0; ks < 2; ks++)
                    acc[i][j] = __builtin_amdgcn_mfma_f32_16x16x32_bf16(af[i][ks], bf[j][ks], acc[i][j], 0, 0, 0);
        __builtin_amdgcn_s_setprio(0);
        __builtin_amdgcn_sched_barrier(0);

        // ---- p1: read bf23 ; stage (kt+1, Bh0) ; MFMA i0-3 j2-3
#pragma unroll
        for (int j = 2; j < 4; j++)
#pragma unroll
            for (int ks = 0; ks < 2; ks++)
                bf[j][ks] = *(const short8*)(&bs[(wn + j * 16 + l16) * 64 + ((((ks << 2) | quad)) ^ swz) * 8]);
        if (st1) STAGE_B(db ^ 1, 0, kt + 1);
        __builtin_amdgcn_sched_barrier(0);
        __builtin_amdgcn_s_setprio(1);
#pragma unroll
        for (int i = 0; i < 4; i++)
#pragma unroll
            for (int j = 2; j < 4; j++)
#pragma unroll
                for (int ks = 0; ks < 2; ks++)
                    acc[i][j] = __builtin_amdgcn_mfma_f32_16x16x32_bf16(af[i][ks], bf[j][ks], acc[i][j], 0, 0, 0);
        __builtin_amdgcn_s_setprio(0);
        __builtin_amdgcn_sched_barrier(0);

        // ---- p2: read af_hi ; stage (kt+1, Bh1) ; MFMA i4-7 j2-3
#pragma unroll
        for (int i = 0; i < 4; i++)
#pragma unroll
            for (int ks = 0; ks < 2; ks++)
                af[i][ks] = *(const short8*)(&as[(wm + 64 + i * 16 + l16) * 64 + ((((ks << 2) | quad)) ^ swz) * 8]);
        if (st1) STAGE_B(db ^ 1, 1, kt + 1);
        __builtin_amdgcn_sched_barrier(0);
        __builtin_amdgcn_s_setprio(1);
#pragma unroll
        for (int i = 0; i < 4; i++)
#pragma unroll
            for (int j = 2; j < 4; j++)
#pragma unroll
                for (int ks = 0; ks < 2; ks++)
                    acc[i + 4][j] = __builtin_amdgcn_mfma_f32_16x16x32_bf16(af[i][ks], bf[j][ks], acc[i + 4][j], 0, 0, 0);
        __builtin_amdgcn_s_setprio(0);
        __builtin_amdgcn_sched_barrier(0);
        // end-p2 barrier: all waves' reads of buf db (incl. Ah0 rows 64-127)
        // are complete -> p3 may overwrite Ah0 of buf db.
        asm volatile("s_barrier" ::: "memory");

        // ---- p3: stage (kt+2, Ah0) into buf db ; MFMA i4-7 j0-1
        if (st2) STAGE_A(db, 0, kt + 2);
        __builtin_amdgcn_sched_barrier(0);
        __builtin_amdgcn_s_setprio(1);
#pragma unroll
        for (int i = 0; i < 4; i++)
#pragma unroll
            for (int j = 0; j < 2; j++)
#pragma unroll
                for (int ks = 0; ks < 2; ks++)
                    acc[i + 4][j] = __builtin_amdgcn_mfma_f32_16x16x32_bf16(af[i][ks], bf[j][ks], acc[i + 4][j], 0, 0, 0);
        __builtin_amdgcn_s_setprio(0);
        __builtin_amdgcn_sched_barrier(0);

        // ---- K-tile boundary: all of (kt+1)'s half-tiles must be landed.
        // Outstanding: (kt+1,Ah1/Bh0/Bh1) + (kt+2,Ah0) -> leave newest 2.
        if (st2) asm volatile("s_waitcnt vmcnt(2)" ::: "memory");
        else     asm volatile("s_waitcnt vmcnt(0)" ::: "memory");
        asm volatile("s_barrier" ::: "memory");
        db ^= 1;
    }

    // epilogue: C/D layout row = quad*4+reg, col = lane&15
#pragma unroll
    for (int i = 0; i < 8; i++) {
        int row = by * 256 + wm + i * 16 + quad * 4;
#pragma unroll
        for (int j = 0; j < 4; j++) {
            int col = bx * 256 + wn + j * 16 + l16;
#pragma unroll
            for (int v = 0; v < 4; v++) {
                float val = acc[i][j][v];
                if (OUT_BF16)
                    ((bf16*)Cv)[coff + (long)(row + v) * ldc + col] = __float2bfloat16(val);
                else
                    ((float*)Cv)[coff + (long)(row + v) * ldc + col] = val;
            }
        }
    }
}

// ---------------------------------------------------------------------------
// OLD reg-staged NT GEMM: kept only for the small Q/K projections
// (N=64 needs bounds guards; A is f32 converted at LDS-store time).
// ---------------------------------------------------------------------------
template<bool OUT_BF16, bool A_F32, bool B_F32>
__global__ void __launch_bounds__(256) gemm_nt(
    const void* __restrict__ Av, const void* __restrict__ Bv, void* __restrict__ Cv,
    int M, int N, int K, int lda, int ldb, int ldc,
    long sA, long sB, long sC)
{
    __shared__ __align__(16) bf16 As[128 * LDK];
    __shared__ __align__(16) bf16 Bs[128 * LDK];

    int bx = blockIdx.x, by = blockIdx.y, bz = blockIdx.z;

    long aoff = (long)bz * sA;
    long boff = (long)bz * sB;
    long coff = (long)bz * sC;

    int m0 = by * 128;
    int n0 = bx * 128;
    int tid  = threadIdx.x;
    int lane = tid & 63;
    int wave = tid >> 6;
    int quad = lane >> 4;
    int l16  = lane & 15;
    int wm = (wave >> 1) * 64;
    int wn = (wave & 1) * 64;

    int sr = tid >> 3;
    int sc = (tid & 7) * 8;

    floatx4 acc[4][4] = {};

    uint4  pa[4], pb[4];
    float4 pa0[4], pa1[4], pb0[4], pb1[4];

    const int nt = K / BK;

#pragma unroll
    for (int s = 0; s < 4; s++) {
        int r = sr + 32 * s;
        int gm = m0 + r;
        if (A_F32) {
            const float* p = (const float*)Av + aoff + (long)gm * lda + sc;
            if (gm < M) { pa0[s] = *(const float4*)p; pa1[s] = *(const float4*)(p + 4); }
            else { pa0[s] = {0,0,0,0}; pa1[s] = {0,0,0,0}; }
        } else {
            pa[s] = (gm < M) ? *(const uint4*)((const bf16*)Av + aoff + (long)gm * lda + sc)
                             : (uint4){0,0,0,0};
        }
        int gn = n0 + r;
        if (B_F32) {
            const float* p = (const float*)Bv + boff + (long)gn * ldb + sc;
            if (gn < N) { pb0[s] = *(const float4*)p; pb1[s] = *(const float4*)(p + 4); }
            else { pb0[s] = {0,0,0,0}; pb1[s] = {0,0,0,0}; }
        } else {
            pb[s] = (gn < N) ? *(const uint4*)((const bf16*)Bv + boff + (long)gn * ldb + sc)
                             : (uint4){0,0,0,0};
        }
    }

    for (int kt = 0; kt < nt; kt++) {
        __syncthreads();
#pragma unroll
        for (int s = 0; s < 4; s++) {
            int r = sr + 32 * s;
            if (A_F32) {
                bf16 t[8];
                t[0]=__float2bfloat16(pa0[s].x); t[1]=__float2bfloat16(pa0[s].y);
                t[2]=__float2bfloat16(pa0[s].z); t[3]=__float2bfloat16(pa0[s].w);
                t[4]=__float2bfloat16(pa1[s].x); t[5]=__float2bfloat16(pa1[s].y);
                t[6]=__float2bfloat16(pa1[s].z); t[7]=__float2bfloat16(pa1[s].w);
                *(uint4*)(&As[r * LDK + sc]) = *(const uint4*)t;
            } else {
                *(uint4*)(&As[r * LDK + sc]) = pa[s];
            }
            if (B_F32) {
                bf16 t[8];
                t[0]=__float2bfloat16(pb0[s].x); t[1]=__float2bfloat16(pb0[s].y);
                t[2]=__float2bfloat16(pb0[s].z); t[3]=__float2bfloat16(pb0[s].w);
                t[4]=__float2bfloat16(pb1[s].x); t[5]=__float2bfloat16(pb1[s].y);
                t[6]=__float2bfloat16(pb1[s].z); t[7]=__float2bfloat16(pb1[s].w);
                *(uint4*)(&Bs[r * LDK + sc]) = *(const uint4*)t;
            } else {
                *(uint4*)(&Bs[r * LDK + sc]) = pb[s];
            }
        }
        __syncthreads();

        if (kt + 1 < nt) {
            int k0 = (kt + 1) * BK;
#pragma unroll
            for (int s = 0; s < 4; s++) {
                int r = sr + 32 * s;
                int gm = m0 + r;
                if (A_F32) {
                    const float* p = (const float*)Av + aoff + (long)gm * lda + k0 + sc;
                    if (gm < M) { pa0[s] = *(const float4*)p; pa1[s] = *(const float4*)(p + 4); }
                    else { pa0[s] = {0,0,0,0}; pa1[s] = {0,0,0,0}; }
                } else {
                    pa[s] = (gm < M) ? *(const uint4*)((const bf16*)Av + aoff + (long)gm * lda + k0 + sc)
                                     : (uint4){0,0,0,0};
                }
                int gn = n0 + r;
                if (B_F32) {
                    const float* p = (const float*)Bv + boff + (long)gn * ldb + k0 + sc;
                    if (gn < N) { pb0[s] = *(const float4*)p; pb1[s] = *(const float4*)(p + 4); }
                    else { pb0[s] = {0,0,0,0}; pb1[s] = {0,0,0,0}; }
                } else {
                    pb[s] = (gn < N) ? *(const uint4*)((const bf16*)Bv + boff + (long)gn * ldb + k0 + sc)
                                     : (uint4){0,0,0,0};
                }
            }
        }

#pragma unroll
        for (int ks = 0; ks < 2; ks++) {
            short8 af[4], bfr[4];
#pragma unroll
            for (int i = 0; i < 4; i++)
                af[i] = *(const short8*)(&As[(wm + i * 16 + l16) * LDK + ks * 32 + quad * 8]);
#pragma unroll
            for (int j = 0; j < 4; j++)
                bfr[j] = *(const short8*)(&Bs[(wn + j * 16 + l16) * LDK + ks * 32 + quad * 8]);
#pragma unroll
            for (int i = 0; i < 4; i++)
#pragma unroll
                for (int j = 0; j < 4; j++)
                    acc[i][j] = __builtin_amdgcn_mfma_f32_16x16x32_bf16(af[i], bfr[j], acc[i][j], 0, 0, 0);
        }
    }

#pragma unroll
    for (int i = 0; i < 4; i++) {
        int row = m0 + wm + i * 16 + quad * 4;
#pragma unroll
        for (int j = 0; j < 4; j++) {
            int col = n0 + wn + j * 16 + l16;
            if (col >= N) continue;
#pragma unroll
            for (int v = 0; v < 4; v++) {
                int r = row + v;
                if (r < M) {
                    float val = acc[i][j][v];
                    if (OUT_BF16)
                        ((bf16*)Cv)[coff + (long)r * ldc + col] = __float2bfloat16(val);
                    else
                        ((float*)Cv)[coff + (long)r * ldc + col] = val;
                }
            }
        }
    }
}

// ---------------------------------------------------------------------------
// Fused QK^T + online softmax, ONE batch (round-4 PROVEN, unchanged).
// ---------------------------------------------------------------------------
__global__ void __launch_bounds__(256) attn_softmax(
    const bf16* __restrict__ Q, const bf16* __restrict__ Kb, bf16* __restrict__ Wts)
{
    __shared__ __align__(16) bf16 Ks[64 * 72];

    int h = blockIdx.y;
    const bf16* Qbh = Q  + (long)h * 262144;
    const bf16* Kbh = Kb + (long)h * 262144;
    bf16* W = Wts + (long)h * 1048576;

    int tid  = threadIdx.x;
    int lane = tid & 63;
    int wave = tid >> 6;
    int quad = lane >> 4;
    int l16  = lane & 15;
    int q0 = blockIdx.x * 64 + wave * 16;

    short8 a0 = *(const short8*)(Qbh + (long)(q0 + l16) * 64 + quad * 8);
    short8 a1 = *(const short8*)(Qbh + (long)(q0 + l16) * 64 + 32 + quad * 8);

    int sr = tid >> 3;
    int sc = (tid & 7) * 8;

    const float scale = 0.125f;
    float m_v[4] = {-1e30f, -1e30f, -1e30f, -1e30f};
    float l_v[4] = {0.f, 0.f, 0.f, 0.f};

    for (int t = 0; t < 16; t++) {
        __syncthreads();
        const bf16* src = Kbh + (long)(t * 64 + sr) * 64 + sc;
        *(uint4*)(&Ks[sr * 72 + sc])        = *(const uint4*)src;
        *(uint4*)(&Ks[(sr + 32) * 72 + sc]) = *(const uint4*)(src + 32 * 64);
        __syncthreads();
#pragma unroll
        for (int j = 0; j < 4; j++) {
            short8 b0 = *(const short8*)(&Ks[(j * 16 + l16) * 72 + quad * 8]);
            short8 b1 = *(const short8*)(&Ks[(j * 16 + l16) * 72 + 32 + quad * 8]);
            floatx4 acc = {0.f, 0.f, 0.f, 0.f};
            acc = __builtin_amdgcn_mfma_f32_16x16x32_bf16(a0, b0, acc, 0, 0, 0);
            acc = __builtin_amdgcn_mfma_f32_16x16x32_bf16(a1, b1, acc, 0, 0, 0);
#pragma unroll
            for (int v = 0; v < 4; v++) {
                float s  = acc[v] * scale;
                float nm = fmaxf(m_v[v], s);
                l_v[v] = l_v[v] * __expf(m_v[v] - nm) + __expf(s - nm);
                m_v[v] = nm;
            }
        }
    }

#pragma unroll
    for (int d = 1; d < 16; d <<= 1) {
#pragma unroll
        for (int v = 0; v < 4; v++) {
            float om = __shfl_xor(m_v[v], d);
            float ol = __shfl_xor(l_v[v], d);
            float nm = fmaxf(m_v[v], om);
            l_v[v] = l_v[v] * __expf(m_v[v] - nm) + ol * __expf(om - nm);
            m_v[v] = nm;
        }
    }
    float linv[4];
#pragma unroll
    for (int v = 0; v < 4; v++) linv[v] = 1.0f / l_v[v];

    for (int t = 0; t < 16; t++) {
        __syncthreads();
        const bf16* src = Kbh + (long)(t * 64 + sr) * 64 + sc;
        *(uint4*)(&Ks[sr * 72 + sc])        = *(const uint4*)src;
        *(uint4*)(&Ks[(sr + 32) * 72 + sc]) = *(const uint4*)(src + 32 * 64);
        __syncthreads();
#pragma unroll
        for (int j = 0; j < 4; j++) {
            short8 b0 = *(const short8*)(&Ks[(j * 16 + l16) * 72 + quad * 8]);
            short8 b1 = *(const short8*)(&Ks[(j * 16 + l16) * 72 + 32 + quad * 8]);
            floatx4 acc = {0.f, 0.f, 0.f, 0.f};
            acc = __builtin_amdgcn_mfma_f32_16x16x32_bf16(a0, b0, acc, 0, 0, 0);
            acc = __builtin_amdgcn_mfma_f32_16x16x32_bf16(a1, b1, acc, 0, 0, 0);
#pragma unroll
            for (int v = 0; v < 4; v++) {
                float w = __expf(acc[v] * scale - m_v[v]) * linv[v];
                W[(long)(q0 + quad * 4 + v) * 1024 + t * 64 + j * 16 + l16] = __float2bfloat16(w);
            }
        }
    }
}

// ---------------------------------------------------------------------------
__global__ void __launch_bounds__(256) cast_bf16_k(
    const float* __restrict__ in, bf16* __restrict__ out, int n4)
{
    int i = blockIdx.x * 256 + threadIdx.x;
    if (i >= n4) return;
    float4 v = ((const float4*)in)[i];
    bf16 t[4] = {__float2bfloat16(v.x), __float2bfloat16(v.y),
                 __float2bfloat16(v.z), __float2bfloat16(v.w)};
    ((uint2*)out)[i] = *(const uint2*)t;
}

__global__ void __launch_bounds__(256) transpose_cast(
    const float* __restrict__ in, bf16* __restrict__ out, int R, int C)
{
    __shared__ float t[32][33];
    int h = blockIdx.z;
    const float* inh = in + (long)h * R * C;
    bf16* outh = out + (long)h * R * C;
    int c0 = blockIdx.x * 32, r0 = blockIdx.y * 32;
    int tx = threadIdx.x, ty = threadIdx.y;
#pragma unroll
    for (int i = 0; i < 32; i += 8)
        t[ty + i][tx] = inh[(long)(r0 + ty + i) * C + c0 + tx];
    __syncthreads();
#pragma unroll
    for (int i = 0; i < 32; i += 8)
        outh[(long)(c0 + ty + i) * R + r0 + tx] = __float2bfloat16(t[tx][ty + i]);
}

// sum 16 fp32 partials of 1M elems each -> out (float4 per thread)
__global__ void __launch_bounds__(256) reduce16_k(
    const float* __restrict__ part, float* __restrict__ out)
{
    int i = blockIdx.x * 256 + threadIdx.x;
    float4 s = ((const float4*)part)[i];
#pragma unroll
    for (int c = 1; c < 16; c++) {
        float4 p = ((const float4*)part)[c * 262144 + i];
        s.x += p.x; s.y += p.y; s.z += p.z; s.w += p.w;
    }
    ((float4*)out)[i] = s;
}

// ---------------------------------------------------------------------------
// Workspace (MB, max 180 — proven):
//   wqt 0..2 | wkt 2..4 | wvt 4..36 | wob 36..68 | qb 68..76 | kb 76..84 |
//   vt_b 84..116 | wts_b 116..148 | att_b 148..180
//   out_part overlays 84..148 (vt_b/wts_b dead when final GEMM runs).
//   value_bf overlays 148..150 (att_b region; dead until PV GEMM, which runs
//   after vt GEMM has consumed value_bf — stream-ordered, safe).
// ---------------------------------------------------------------------------
extern "C" void kernel_launch(void* const* d_in, const int* in_sizes, int n_in,
                              void* d_out, int out_size, void* d_ws, size_t ws_size,
                              hipStream_t stream) {
    const float* query = (const float*)d_in[0];
    const float* key   = (const float*)d_in[1];
    const float* value = (const float*)d_in[2];
    const float* w_q   = (const float*)d_in[3];
    const float* w_k   = (const float*)d_in[4];
    const float* w_v   = (const float*)d_in[5];
    const float* w_o   = (const float*)d_in[6];
    float* out = (float*)d_out;

    char* ws = (char*)d_ws;
    const size_t MB = (size_t)1 << 20;
    bf16* wqt      = (bf16*)(ws + 0 * MB);
    bf16* wkt      = (bf16*)(ws + 2 * MB);
    bf16* wvt      = (bf16*)(ws + 4 * MB);
    bf16* wob      = (bf16*)(ws + 36 * MB);
    bf16* qb       = (bf16*)(ws + 68 * MB);
    bf16* kb       = (bf16*)(ws + 76 * MB);
    bf16* vt_b     = (bf16*)(ws + 84 * MB);
    bf16* wts_b    = (bf16*)(ws + 116 * MB);
    bf16* att_b    = (bf16*)(ws + 148 * MB);
    bf16* value_bf = (bf16*)(ws + 148 * MB);    // 2 MB overlay on att_b head
    float* out_part = (float*)(ws + 84 * MB);   // 64 MB overlay

    // weight prep
    transpose_cast<<<dim3(2, 32, 16),  dim3(32, 8), 0, stream>>>(w_q, wqt, 1024, 64);
    transpose_cast<<<dim3(2, 32, 16),  dim3(32, 8), 0, stream>>>(w_k, wkt, 1024, 64);
    transpose_cast<<<dim3(32, 32, 16), dim3(32, 8), 0, stream>>>(w_v, wvt, 1024, 1024);
    cast_bf16_k<<<16384, 256, 0, stream>>>(w_o, wob, 1024 * 16384 / 4);

    // Q/K projections (small, N=64 — old guarded reg-staged path)
    gemm_nt<true, true, false><<<dim3(1, 32, 16), 256, 0, stream>>>(
        query, wqt, qb, 4096, 64, 1024, 1024, 1024, 64, 0L, 65536L, 262144L);
    gemm_nt<true, true, false><<<dim3(1, 32, 16), 256, 0, stream>>>(
        key, wkt, kb, 4096, 64, 1024, 1024, 1024, 64, 0L, 65536L, 262144L);

    for (int b = 0; b < 4; b++) {
        // cast this batch's value to bf16 (enables global_load_lds path)
        cast_bf16_k<<<1024, 256, 0, stream>>>(value + (long)b * 1048576, value_bf, 262144);

        // V^T proj: vt_b[h][v][m] = wvt[h][v][d] . value_b[m][d]^T
        gemm_nt_256<true><<<dim3(4, 4, 16), 512, 0, stream>>>(
            wvt, value_bf, vt_b,
            1024, 1024, 1024, 1024, 1048576L, 0L, 1048576L);

        // QK^T + softmax -> wts_b[h][q][m]
        attn_softmax<<<dim3(16, 16), 256, 0, stream>>>(
            qb + (long)b * 65536, kb + (long)b * 65536, wts_b);

        // PV^T: att_b[v][h*1024+q] = vt_b[h][v][m] . wts_b[h][q][m]^T
        gemm_nt_256<true><<<dim3(4, 4, 16), 512, 0, stream>>>(
            vt_b, wts_b, att_b,
            1024, 1024, 1024, 16384, 1048576L, 1048576L, 1024L);

        // final split-K over heads: out_part[h][d][v] = wo[d][h*1024+q] . att_b[v][h*1024+q]^T
        gemm_nt_256<false><<<dim3(4, 4, 16), 512, 0, stream>>>(
            wob, att_b, out_part,
            1024, 16384, 16384, 1024, 1024L, 1024L, 1048576L);

        // reduce 16 partials -> out[b]
        reduce16_k<<<1024, 256, 0, stream>>>(out_part, out + (long)b * 1048576);
    }

    (void)in_sizes; (void)n_in; (void)out_size; (void)ws_size;
}